// Round 3
// baseline (936.626 us; speedup 1.0000x reference)
//
#include <hip/hip_runtime.h>

#define HASH_SIZE 256
#define OFFSET_SIZE 64
#define FEAT 8
#define OT_ENTRIES (OFFSET_SIZE * OFFSET_SIZE * OFFSET_SIZE)

// Clang ext_vector types — __builtin_nontemporal_* accepts these
// (it rejects HIP_vector_type int4/float4).
typedef int   iv4 __attribute__((ext_vector_type(4)));
typedef float fv4 __attribute__((ext_vector_type(4)));

// Pre-pack offset_table (int32 x3 per entry, values only matter mod 256) into
// one u32 per entry: dx | dy<<8 | dz<<16.  (h+d)%256 depends only on d&255, so
// this is exact.  Shrinks the gather table 3 MB -> 1 MB (fully L2-resident per
// XCD) and turns 3 divergent dword gathers into 1.
__global__ void __launch_bounds__(256)
pack_offsets_kernel(const int* __restrict__ offset_table,
                    unsigned int* __restrict__ packed) {
    int i = blockIdx.x * blockDim.x + threadIdx.x;
    if (i >= OT_ENTRIES) return;
    unsigned dx = (unsigned)offset_table[3 * i + 0] & 255u;
    unsigned dy = (unsigned)offset_table[3 * i + 1] & 255u;
    unsigned dz = (unsigned)offset_table[3 * i + 2] & 255u;
    packed[i] = dx | (dy << 8) | (dz << 16);
}

// 4 queries per thread:
//  - coords loads become 3x aligned 16B vectors (48 B contiguous per thread)
//  - 4 independent offset gathers issued back-to-back, then 8 independent
//    hash-table 16B gathers -> 4x the memory-level parallelism of the
//    1-query/thread chain (which had <=2-3 outstanding VMEM per wave).
//  - out stores become 128 B contiguous per thread (8x 16B), nontemporal
//    so the 128 MB streaming write doesn't evict hash lines from L2/L3.
template <bool PACKED>
__global__ void __launch_bounds__(256)
psh_kernel4(const int* __restrict__ coords,
            const float* __restrict__ hash_table,
            const int* __restrict__ offset_table,
            const unsigned int* __restrict__ offset_packed,
            const float* __restrict__ m0,
            const float* __restrict__ m1,
            float* __restrict__ out,
            int n) {
    int t = blockIdx.x * blockDim.x + threadIdx.x;
    int base = t * 4;
    if (base >= n) return;

    // Wave-uniform; compiler hoists to scalar loads.
    float m0x = m0[0], m0y = m0[1], m0z = m0[2];
    float m1x = m1[0], m1y = m1[1], m1z = m1[2];

    if (base + 4 <= n) {
        // ---- coords: 12 ints = 3 aligned 16B vectors, nontemporal ----
        const iv4* c4 = (const iv4*)(coords + (size_t)base * 3);
        iv4 va = __builtin_nontemporal_load(c4 + 0);  // q0.xyz q1.x
        iv4 vb = __builtin_nontemporal_load(c4 + 1);  // q1.yz  q2.xy
        iv4 vc = __builtin_nontemporal_load(c4 + 2);  // q2.z   q3.xyz
        int cx[4] = {va.x, va.w, vb.z, vc.y};
        int cy[4] = {va.y, vb.x, vb.w, vc.z};
        int cz[4] = {va.z, vb.y, vc.x, vc.w};

        // ---- 4 independent offset gathers ----
        int dx[4], dy[4], dz[4];
        if (PACKED) {
            unsigned pk[4];
#pragma unroll
            for (int q = 0; q < 4; ++q) {
                int ox = ((int)((float)cx[q] * m1x)) & (OFFSET_SIZE - 1);
                int oy = ((int)((float)cy[q] * m1y)) & (OFFSET_SIZE - 1);
                int oz = ((int)((float)cz[q] * m1z)) & (OFFSET_SIZE - 1);
                pk[q] = offset_packed[(ox * OFFSET_SIZE + oy) * OFFSET_SIZE + oz];
            }
#pragma unroll
            for (int q = 0; q < 4; ++q) {
                dx[q] = (int)(pk[q] & 255u);
                dy[q] = (int)((pk[q] >> 8) & 255u);
                dz[q] = (int)((pk[q] >> 16) & 255u);
            }
        } else {
#pragma unroll
            for (int q = 0; q < 4; ++q) {
                int ox = ((int)((float)cx[q] * m1x)) & (OFFSET_SIZE - 1);
                int oy = ((int)((float)cy[q] * m1y)) & (OFFSET_SIZE - 1);
                int oz = ((int)((float)cz[q] * m1z)) & (OFFSET_SIZE - 1);
                size_t ooff = ((size_t)((ox * OFFSET_SIZE + oy) * OFFSET_SIZE + oz)) * 3;
                dx[q] = offset_table[ooff + 0];
                dy[q] = offset_table[ooff + 1];
                dz[q] = offset_table[ooff + 2];
            }
        }

        // ---- 8 independent hash-table gathers (4 queries x 16 B x 2) ----
        fv4 f[8];
#pragma unroll
        for (int q = 0; q < 4; ++q) {
            int hx = (((int)((float)cx[q] * m0x)) + dx[q]) & (HASH_SIZE - 1);
            int hy = (((int)((float)cy[q] * m0y)) + dy[q]) & (HASH_SIZE - 1);
            int hz = (((int)((float)cz[q] * m0z)) + dz[q]) & (HASH_SIZE - 1);
            const fv4* hp = (const fv4*)(hash_table +
                (((size_t)hx * HASH_SIZE + hy) * HASH_SIZE + hz) * FEAT);
            f[2 * q + 0] = hp[0];
            f[2 * q + 1] = hp[1];
        }

        // ---- out: 128 B contiguous per thread, nontemporal ----
        fv4* o4 = (fv4*)(out + (size_t)base * FEAT);
#pragma unroll
        for (int j = 0; j < 8; ++j)
            __builtin_nontemporal_store(f[j], o4 + j);
    } else {
        // Scalar tail (n not divisible by 4).
        for (int i = base; i < n; ++i) {
            int cx = coords[3 * i + 0];
            int cy = coords[3 * i + 1];
            int cz = coords[3 * i + 2];
            int ox = ((int)((float)cx * m1x)) & (OFFSET_SIZE - 1);
            int oy = ((int)((float)cy * m1y)) & (OFFSET_SIZE - 1);
            int oz = ((int)((float)cz * m1z)) & (OFFSET_SIZE - 1);
            int dx, dy, dz;
            if (PACKED) {
                unsigned pk = offset_packed[(ox * OFFSET_SIZE + oy) * OFFSET_SIZE + oz];
                dx = (int)(pk & 255u);
                dy = (int)((pk >> 8) & 255u);
                dz = (int)((pk >> 16) & 255u);
            } else {
                size_t ooff = ((size_t)((ox * OFFSET_SIZE + oy) * OFFSET_SIZE + oz)) * 3;
                dx = offset_table[ooff + 0];
                dy = offset_table[ooff + 1];
                dz = offset_table[ooff + 2];
            }
            int hx = (((int)((float)cx * m0x)) + dx) & (HASH_SIZE - 1);
            int hy = (((int)((float)cy * m0y)) + dy) & (HASH_SIZE - 1);
            int hz = (((int)((float)cz * m0z)) + dz) & (HASH_SIZE - 1);
            const fv4* hp = (const fv4*)(hash_table +
                (((size_t)hx * HASH_SIZE + hy) * HASH_SIZE + hz) * FEAT);
            fv4* o4 = (fv4*)(out + (size_t)i * FEAT);
            o4[0] = hp[0];
            o4[1] = hp[1];
        }
    }
}

extern "C" void kernel_launch(void* const* d_in, const int* in_sizes, int n_in,
                              void* d_out, int out_size, void* d_ws, size_t ws_size,
                              hipStream_t stream) {
    const int*   coords       = (const int*)d_in[0];
    const float* hash_table   = (const float*)d_in[1];
    const int*   offset_table = (const int*)d_in[2];
    const float* m0           = (const float*)d_in[3];
    const float* m1           = (const float*)d_in[4];
    float*       out          = (float*)d_out;

    int n = in_sizes[0] / 3;  // 4,000,000 queries

    size_t need = (size_t)OT_ENTRIES * sizeof(unsigned int);
    bool packed = (d_ws != nullptr) && (ws_size >= need);

    if (packed) {
        pack_offsets_kernel<<<(OT_ENTRIES + 255) / 256, 256, 0, stream>>>(
            offset_table, (unsigned int*)d_ws);
    }

    int nthreads = (n + 3) / 4;
    int block = 256;
    int grid = (nthreads + block - 1) / block;
    if (packed) {
        psh_kernel4<true><<<grid, block, 0, stream>>>(
            coords, hash_table, offset_table, (const unsigned int*)d_ws,
            m0, m1, out, n);
    } else {
        psh_kernel4<false><<<grid, block, 0, stream>>>(
            coords, hash_table, offset_table, nullptr,
            m0, m1, out, n);
    }
}